// Round 22
// baseline (183.467 us; speedup 1.0000x reference)
//
#include <hip/hip_runtime.h>
#include <math.h>

#define C 128
#define OVF_CAP 32768

typedef unsigned short ushort_t;
typedef short short8 __attribute__((ext_vector_type(8)));
typedef float floatx4 __attribute__((ext_vector_type(4)));
typedef float fx2 __attribute__((ext_vector_type(2)));

__device__ __forceinline__ ushort_t f2bf(float x) {
  unsigned u = __float_as_uint(x);
  unsigned r = (u + 0x7FFFu + ((u >> 16) & 1u)) >> 16;
  return (ushort_t)r;
}
__device__ __forceinline__ fx2 bf2f2(unsigned u) {
  fx2 r;
  r.x = __uint_as_float(u << 16);
  r.y = __uint_as_float(u & 0xFFFF0000u);
  return r;
}

// ---------------- K0: init ws + weight prep ----------------

__global__ void k_init_prep(int* __restrict__ deg, int* __restrict__ mark,
                            float* __restrict__ lossacc,
                            unsigned* __restrict__ done_cnt, int* __restrict__ ncnt,
                            int* __restrict__ ovf_cnt, int n,
                            const float* __restrict__ Wl, const float* __restrict__ Wr,
                            const float* __restrict__ W1,
                            ushort_t* __restrict__ wcat, ushort_t* __restrict__ w1t) {
  int idx = blockIdx.x * blockDim.x + threadIdx.x;
  if (idx < n) { deg[idx] = 0; mark[idx] = 0; }
  if (idx == 0) { lossacc[0] = 0.f; done_cnt[0] = 0u; ncnt[0] = 0; ovf_cnt[0] = 0; }
  const int NCAT = 2 * 256 * 128;
  if (idx < NCAT) {
    int l = idx >> 15;
    int rem = idx & 32767;
    int nn = rem >> 7;
    int k = rem & 127;
    float v = (nn < 128) ? Wl[l * C * C + k * C + nn] : Wr[l * C * C + k * C + (nn - 128)];
    wcat[idx] = f2bf(v);
  } else if (idx < NCAT + 128 * 256) {
    int j = idx - NCAT;
    int nn = j >> 8;
    int k = j & 255;
    w1t[j] = f2bf(W1[k * C + nn]);
  }
}

// ---------------- bf16 MFMA GEMM (A = bf16 or f32 with in-reg convert) ----------------

__device__ __forceinline__ void gemm_body(
    const ushort_t* __restrict__ A, const float* __restrict__ Af,
    const ushort_t* __restrict__ Bt, int M, int K,
    ushort_t* __restrict__ outb0, ushort_t* __restrict__ outb1,
    int bx, int by) {
  int tid = threadIdx.x;
  int wave = tid >> 6, lane = tid & 63;
  int wm = (wave >> 1) * 64, wn = (wave & 1) * 64;
  int m_base = bx * 128 + wm;
  int lrow = lane & 15, lkg = lane >> 4;

  floatx4 acc[4][4];
  #pragma unroll
  for (int mi = 0; mi < 4; mi++)
    #pragma unroll
    for (int ni = 0; ni < 4; ni++)
      acc[mi][ni] = (floatx4){0.f, 0.f, 0.f, 0.f};

  const int ksteps = K >> 5;
  for (int ks = 0; ks < ksteps; ks++) {
    int koff = ks * 32 + lkg * 8;
    short8 af[4], bfr[4];
    #pragma unroll
    for (int mi = 0; mi < 4; mi++) {
      int gm = m_base + mi * 16 + lrow;
      gm = (gm < M) ? gm : (M - 1);
      if (Af) {
        const float* src = &Af[(size_t)gm * K + koff];
        float4 lo = *(const float4*)src;
        float4 hi = *(const float4*)(src + 4);
        short8 a;
        a[0] = (short)f2bf(lo.x); a[1] = (short)f2bf(lo.y);
        a[2] = (short)f2bf(lo.z); a[3] = (short)f2bf(lo.w);
        a[4] = (short)f2bf(hi.x); a[5] = (short)f2bf(hi.y);
        a[6] = (short)f2bf(hi.z); a[7] = (short)f2bf(hi.w);
        af[mi] = a;
      } else {
        af[mi] = *(const short8*)&A[(size_t)gm * K + koff];
      }
    }
    #pragma unroll
    for (int ni = 0; ni < 4; ni++) {
      int gn = by * 128 + wn + ni * 16 + lrow;
      bfr[ni] = *(const short8*)&Bt[(size_t)gn * K + koff];
    }
    #pragma unroll
    for (int mi = 0; mi < 4; mi++)
      #pragma unroll
      for (int ni = 0; ni < 4; ni++)
        acc[mi][ni] = __builtin_amdgcn_mfma_f32_16x16x32_bf16(af[mi], bfr[ni], acc[mi][ni], 0, 0, 0);
  }

  ushort_t* outb = (by == 0) ? outb0 : outb1;
  #pragma unroll
  for (int mi = 0; mi < 4; mi++) {
    #pragma unroll
    for (int r = 0; r < 4; r++) {
      int gm = m_base + mi * 16 + lkg * 4 + r;
      if (gm >= M) continue;
      #pragma unroll
      for (int ni = 0; ni < 4; ni++) {
        int nl = wn + ni * 16 + lrow;
        outb[(size_t)gm * 128 + nl] = f2bf(acc[mi][ni][r]);
      }
    }
  }
}

__global__ __launch_bounds__(256) void gemm_mfma(
    const ushort_t* __restrict__ A, const ushort_t* __restrict__ Bt,
    int M, int K,
    ushort_t* __restrict__ outb0, ushort_t* __restrict__ outb1) {
  gemm_body(A, nullptr, Bt, M, K, outb0, outb1, blockIdx.x, blockIdx.y);
}

// ---------------- K2: hist+scatter (FIRST) ∪ gemm layer-0 (f32 A) ∪ pair-dedup ----------------
// Edge blocks at low blockIdx so they dispatch first and span the kernel;
// gemm MFMA blocks fill in behind and overlap the edge tail.

__global__ __launch_bounds__(256) void k_gemm_scatter(
    const float* __restrict__ x, const ushort_t* __restrict__ Bt,
    int M, int K,
    ushort_t* __restrict__ outb0, ushort_t* __restrict__ outb1, int sx, int gb,
    const int* __restrict__ ei, int* __restrict__ deg,
    int* __restrict__ col32, int* __restrict__ ovf, int* __restrict__ ovf_cnt,
    int E, int ET,
    const int* __restrict__ tp, const int* __restrict__ fp, int npair2,
    int* __restrict__ mark, int* __restrict__ nlist, int* __restrict__ ncnt) {
  int bx = blockIdx.x;
  if (bx < sx) {
    int chunk = bx * 2 + blockIdx.y;
    int e = chunk * 256 + threadIdx.x;
    if (e < ET) {
      int s, d;
      if (e < E) { s = ei[e]; d = ei[E + e]; }
      else { s = e - E; d = e - E; }        // self loop
      int p = atomicAdd(&deg[d], 1);
      if (p < 32) {
        col32[(d << 5) + p] = s;
      } else {
        int k = atomicAdd(ovf_cnt, 1);
        if (k < OVF_CAP) { ovf[2 * k] = d; ovf[2 * k + 1] = s; }
      }
    }
  } else if (bx < sx + gb) {
    gemm_body(nullptr, x, Bt, M, K, outb0, outb1, bx - sx, blockIdx.y);
  } else {
    int chunk = (bx - sx - gb) * 2 + blockIdx.y;
    int i = chunk * 256 + threadIdx.x;
    if (i < 2 * npair2) {                   // dedup-append pair nodes
      int node = (i < npair2) ? tp[i] : fp[i - npair2];
      if (atomicExch(&mark[node], 1) == 0) {
        int k = atomicAdd(ncnt, 1);
        nlist[k] = node;
      }
    }
  }
}

// ---------------- GATv2 fused edge softmax + aggregation ----------------
// One wave per dst node; 4 groups x 16 lanes x 2 edges/iter. Fixed 32-slot
// CSR; slot loads unconditional with unsigned clamp. Overflow edges from
// tiny list, group-0 masked. exp2-domain logits. nlist: restricted mode.

__global__ __launch_bounds__(256) void gat_aggregate(
    const ushort_t* __restrict__ xl, const ushort_t* __restrict__ xr,
    const int* __restrict__ deg, const int* __restrict__ col32,
    const int* __restrict__ ovf, const int* __restrict__ ovf_cnt,
    const float* __restrict__ att, const float* __restrict__ bias,
    float* __restrict__ houtf, ushort_t* __restrict__ houtb,
    const int* __restrict__ nlist, const int* __restrict__ ncnt,
    int n, int do_relu) {
  int gwid = (int)((blockIdx.x * (size_t)blockDim.x + threadIdx.x) >> 6);
  int lane = threadIdx.x & 63;
  int wid;
  if (nlist) {
    if (gwid >= ncnt[0]) return;
    wid = nlist[gwid];
  } else {
    if (gwid >= n) return;
    wid = gwid;
  }
  int g = lane >> 4, p = lane & 15;
  int c0 = p * 8;
  const size_t i = wid;

  fx2 xri[4], av[4];
  {
    uint4 ur = *(const uint4*)&xr[i * C + c0];
    xri[0] = bf2f2(ur.x); xri[1] = bf2f2(ur.y);
    xri[2] = bf2f2(ur.z); xri[3] = bf2f2(ur.w);
    float4 a0 = *(const float4*)&att[c0];
    float4 a1 = *(const float4*)&att[c0 + 4];
    const float L2E = 1.44269504088896f;     // exp2-domain logits
    av[0] = (fx2){a0.x * L2E, a0.y * L2E}; av[1] = (fx2){a0.z * L2E, a0.w * L2E};
    av[2] = (fx2){a1.x * L2E, a1.y * L2E}; av[3] = (fx2){a1.z * L2E, a1.w * L2E};
  }

  int degc = deg[wid];
  int beg = wid << 5;
  int dmain = (degc < 32) ? degc : 32;
  int end = beg + dmain;
  float denom = 0.f;
  fx2 acc[4];
  #pragma unroll
  for (int q = 0; q < 4; q++) acc[q] = (fx2){0.f, 0.f};

  for (int base = beg; base < end; base += 8) {
    int e0 = base + g;
    int e1 = e0 + 4;
    unsigned j0 = min((unsigned)col32[e0], (unsigned)(n - 1));  // unconditional + clamp
    unsigned j1 = min((unsigned)col32[e1], (unsigned)(n - 1));
    uint4 r0 = *(const uint4*)&xl[((size_t)j0 << 7) + c0];
    uint4 r1 = *(const uint4*)&xl[((size_t)j1 << 7) + c0];
    fx2 x0[4], x1[4];
    x0[0] = bf2f2(r0.x); x0[1] = bf2f2(r0.y); x0[2] = bf2f2(r0.z); x0[3] = bf2f2(r0.w);
    x1[0] = bf2f2(r1.x); x1[1] = bf2f2(r1.y); x1[2] = bf2f2(r1.z); x1[3] = bf2f2(r1.w);

    fx2 d0 = (fx2){0.f, 0.f}, d1 = (fx2){0.f, 0.f};
    #pragma unroll
    for (int q = 0; q < 4; q++) {
      fx2 z0 = x0[q] + xri[q];
      fx2 z1 = x1[q] + xri[q];
      z0 = __builtin_elementwise_max(z0, z0 * 0.2f);
      z1 = __builtin_elementwise_max(z1, z1 * 0.2f);
      d0 = __builtin_elementwise_fma(z0, av[q], d0);
      d1 = __builtin_elementwise_fma(z1, av[q], d1);
    }
    float p0 = d0.x + d0.y;
    float p1 = d1.x + d1.y;
    #pragma unroll
    for (int off = 1; off <= 8; off <<= 1) {
      p0 += __shfl_xor(p0, off);
      p1 += __shfl_xor(p1, off);
    }
    float pe0 = (e0 < end) ? __builtin_amdgcn_exp2f(p0) : 0.f;
    float pe1 = (e1 < end) ? __builtin_amdgcn_exp2f(p1) : 0.f;
    denom += pe0 + pe1;
    fx2 v0 = (fx2){pe0, pe0}, v1 = (fx2){pe1, pe1};
    #pragma unroll
    for (int q = 0; q < 4; q++) {
      acc[q] = __builtin_elementwise_fma(v0, x0[q], acc[q]);
      acc[q] = __builtin_elementwise_fma(v1, x1[q], acc[q]);
    }
  }

  if (degc > 32) {                          // rare
    int oc = ovf_cnt[0];
    oc = (oc < OVF_CAP) ? oc : OVF_CAP;
    for (int t = 0; t < oc; t++) {
      if (ovf[2 * t] != wid) continue;
      unsigned j0 = min((unsigned)ovf[2 * t + 1], (unsigned)(n - 1));
      uint4 r0 = *(const uint4*)&xl[((size_t)j0 << 7) + c0];
      fx2 x0[4];
      x0[0] = bf2f2(r0.x); x0[1] = bf2f2(r0.y); x0[2] = bf2f2(r0.z); x0[3] = bf2f2(r0.w);
      fx2 d0 = (fx2){0.f, 0.f};
      #pragma unroll
      for (int q = 0; q < 4; q++) {
        fx2 z0 = x0[q] + xri[q];
        z0 = __builtin_elementwise_max(z0, z0 * 0.2f);
        d0 = __builtin_elementwise_fma(z0, av[q], d0);
      }
      float p0 = d0.x + d0.y;
      #pragma unroll
      for (int off = 1; off <= 8; off <<= 1)
        p0 += __shfl_xor(p0, off);
      float pe = (g == 0) ? __builtin_amdgcn_exp2f(p0) : 0.f;  // count once
      denom += pe;
      fx2 v0 = (fx2){pe, pe};
      #pragma unroll
      for (int q = 0; q < 4; q++)
        acc[q] = __builtin_elementwise_fma(v0, x0[q], acc[q]);
    }
  }

  #pragma unroll
  for (int off = 16; off <= 32; off <<= 1) {
    denom += __shfl_xor(denom, off);
    #pragma unroll
    for (int q = 0; q < 4; q++) {
      acc[q].x += __shfl_xor(acc[q].x, off);
      acc[q].y += __shfl_xor(acc[q].y, off);
    }
  }

  if (g == 0) {
    float inv = 1.f / denom;            // degree >= 1 via self loop
    float4 b0 = *(const float4*)&bias[c0];
    float4 b1 = *(const float4*)&bias[c0 + 4];
    float o[8];
    o[0] = acc[0].x*inv + b0.x; o[1] = acc[0].y*inv + b0.y;
    o[2] = acc[1].x*inv + b0.z; o[3] = acc[1].y*inv + b0.w;
    o[4] = acc[2].x*inv + b1.x; o[5] = acc[2].y*inv + b1.y;
    o[6] = acc[3].x*inv + b1.z; o[7] = acc[3].y*inv + b1.w;
    if (do_relu) {
      #pragma unroll
      for (int c = 0; c < 8; c++) o[c] = fmaxf(o[c], 0.f);
    }
    if (houtf) {
      *(float4*)&houtf[i * C + c0]     = make_float4(o[0], o[1], o[2], o[3]);
      *(float4*)&houtf[i * C + c0 + 4] = make_float4(o[4], o[5], o[6], o[7]);
    } else {
      short8 s;
      #pragma unroll
      for (int c = 0; c < 8; c++) s[c] = (short)f2bf(o[c]);
      *(short8*)&houtb[i * C + c0] = s;
    }
  }
}

// ---------------- scorer: fused pair-gather + GEMM + probs + loss ----------------

__global__ __launch_bounds__(256) void gemm_scorer(
    const float* __restrict__ h, const int* __restrict__ tp, const int* __restrict__ fp,
    const ushort_t* __restrict__ w1t, float* __restrict__ out_pos,
    const float* __restrict__ b1, const float* __restrict__ W2,
    const float* __restrict__ b2, float* __restrict__ probs_out,
    float* __restrict__ lossacc, unsigned* __restrict__ done_cnt,
    float* __restrict__ out_loss, int P2, int P) {
  __shared__ float lhalf[2][128];
  __shared__ float red[128];
  int tid = threadIdx.x;
  int wave = tid >> 6, lane = tid & 63;
  int wm = (wave >> 1) * 64, wn = (wave & 1) * 64;
  int m_base = blockIdx.x * 128 + wm;
  int lrow = lane & 15, lkg = lane >> 4;
  int half = P2 >> 1;
  bool emit = (wn == 0);

  int n0[4], n1[4];
  #pragma unroll
  for (int mi = 0; mi < 4; mi++) {
    int gm = m_base + mi * 16 + lrow;
    const int* pr = (gm < half) ? &tp[(size_t)gm * 2] : &fp[(size_t)(gm - half) * 2];
    n0[mi] = pr[0];
    n1[mi] = pr[1];
  }

  floatx4 acc[4][4];
  #pragma unroll
  for (int mi = 0; mi < 4; mi++)
    #pragma unroll
    for (int ni = 0; ni < 4; ni++)
      acc[mi][ni] = (floatx4){0.f, 0.f, 0.f, 0.f};

  #pragma unroll
  for (int ks = 0; ks < 8; ks++) {
    int koff = ks * 32 + lkg * 8;        // 0..248; ks<4 -> first node
    int chan = koff & 127;
    short8 af[4], bfr[4];
    #pragma unroll
    for (int mi = 0; mi < 4; mi++) {
      int node = (ks < 4) ? n0[mi] : n1[mi];
      const float* src = &h[(size_t)node * C + chan];
      float4 lo = *(const float4*)src;
      float4 hi = *(const float4*)(src + 4);
      if (emit) {
        int gm = m_base + mi * 16 + lrow;
        *(float4*)&out_pos[(size_t)gm * 256 + koff]     = lo;
        *(float4*)&out_pos[(size_t)gm * 256 + koff + 4] = hi;
      }
      short8 a;
      a[0] = (short)f2bf(lo.x); a[1] = (short)f2bf(lo.y);
      a[2] = (short)f2bf(lo.z); a[3] = (short)f2bf(lo.w);
      a[4] = (short)f2bf(hi.x); a[5] = (short)f2bf(hi.y);
      a[6] = (short)f2bf(hi.z); a[7] = (short)f2bf(hi.w);
      af[mi] = a;
    }
    #pragma unroll
    for (int ni = 0; ni < 4; ni++) {
      int gn = wn + ni * 16 + lrow;
      bfr[ni] = *(const short8*)&w1t[(size_t)gn * 256 + koff];
    }
    #pragma unroll
    for (int mi = 0; mi < 4; mi++)
      #pragma unroll
      for (int ni = 0; ni < 4; ni++)
        acc[mi][ni] = __builtin_amdgcn_mfma_f32_16x16x32_bf16(af[mi], bfr[ni], acc[mi][ni], 0, 0, 0);
  }

  // epilogue: hid = relu(acc + b1); partial W2-dot per wave-half in-register
  float b1v[4], w2v[4];
  #pragma unroll
  for (int ni = 0; ni < 4; ni++) {
    int nl = wn + ni * 16 + lrow;
    b1v[ni] = b1[nl];
    w2v[ni] = W2[nl];
  }
  #pragma unroll
  for (int mi = 0; mi < 4; mi++) {
    #pragma unroll
    for (int r = 0; r < 4; r++) {
      float ps = 0.f;
      #pragma unroll
      for (int ni = 0; ni < 4; ni++) {
        float v = fmaxf(acc[mi][ni][r] + b1v[ni], 0.f);
        ps = fmaf(v, w2v[ni], ps);
      }
      #pragma unroll
      for (int off = 1; off <= 8; off <<= 1)
        ps += __shfl_xor(ps, off);
      if (lrow == 0)
        lhalf[wn ? 1 : 0][wm + mi * 16 + lkg * 4 + r] = ps;
    }
  }
  __syncthreads();

  float term = 0.f;
  if (tid < 128) {
    int gr = blockIdx.x * 128 + tid;
    float s = lhalf[0][tid] + lhalf[1][tid] + b2[0];
    float pv = 1.f / (1.f + expf(-s));
    probs_out[gr] = pv;
    float pcl = fminf(fmaxf(pv, 1e-7f), 1.f - 1e-7f);
    term = (gr < P) ? logf(pcl) : log1pf(-pcl);
    red[tid] = term;
  }
  __syncthreads();
  if (tid < 64) red[tid] += red[tid + 64];
  __syncthreads();
  if (tid < 32) red[tid] += red[tid + 32];
  __syncthreads();
  if (tid == 0) {
    float s = 0.f;
    #pragma unroll
    for (int k = 0; k < 32; k++) s += red[k];
    atomicAdd(lossacc, s);
    __threadfence();
    unsigned prev = atomicAdd(done_cnt, 1u);
    if (prev == gridDim.x - 1) {
      float total = atomicAdd(lossacc, 0.f);    // coherent read
      out_loss[0] = -total / (float)P2;
    }
  }
}

// ---------------- launch ----------------

extern "C" void kernel_launch(void* const* d_in, const int* in_sizes, int n_in,
                              void* d_out, int out_size, void* d_ws, size_t ws_size,
                              hipStream_t stream) {
  const float* x    = (const float*)d_in[0];
  const int*   ei   = (const int*)d_in[1];
  const int*   tp   = (const int*)d_in[2];
  const int*   fp   = (const int*)d_in[3];
  const float* Wl   = (const float*)d_in[4];
  const float* Wr   = (const float*)d_in[5];
  const float* att  = (const float*)d_in[6];
  const float* bias = (const float*)d_in[7];
  const float* W1   = (const float*)d_in[8];
  const float* b1   = (const float*)d_in[9];
  const float* W2   = (const float*)d_in[10];
  const float* b2   = (const float*)d_in[11];

  int N  = in_sizes[0] / C;    // 50000
  int E  = in_sizes[1] / 2;    // 800000
  int P  = in_sizes[2] / 2;    // 8192
  int ET = E + N;
  int P2 = 2 * P;
  int npair2 = 2 * P;          // entries per pair array (P x 2)

  float* out       = (float*)d_out;
  float* out_pos   = out;                                  // [2P, 2C] (pos then neg)
  float* out_probs = out + (size_t)P2 * 2 * C;
  float* out_loss  = out_probs + P2;

  char* w = (char*)d_ws;
  size_t NCb2 = (size_t)N * C * 2;                         // bf16 [N,C]
  ushort_t* xl_bf = (ushort_t*)w;  w += NCb2;
  ushort_t* xr_bf = (ushort_t*)w;  w += NCb2;
  ushort_t* h1_bf = (ushort_t*)w;  w += NCb2;
  float* h1f = (float*)w;          w += (size_t)N * C * 4;
  ushort_t* wcat = (ushort_t*)w;   w += (size_t)2 * 256 * 128 * 2;
  ushort_t* w1t  = (ushort_t*)w;   w += (size_t)128 * 256 * 2;
  int* deg     = (int*)w;  w += (size_t)N * 4;
  int* mark    = (int*)w;  w += (size_t)N * 4;
  int* nlist   = (int*)w;  w += (size_t)(2 * npair2) * 4;
  int* col32   = (int*)w;  w += (size_t)N * 32 * 4;        // fixed-stride CSR slots
  int* ovf     = (int*)w;  w += (size_t)OVF_CAP * 2 * 4;   // overflow (d,s) pairs
  float* lossacc = (float*)w;  w += 16;
  unsigned* done_cnt = (unsigned*)w;  w += 16;
  int* ncnt    = (int*)w;  w += 16;
  int* ovf_cnt = (int*)w;

  const int tB = 256;

  // K0: init + weight prep
  k_init_prep<<<384, tB, 0, stream>>>(deg, mark, lossacc, done_cnt, ncnt, ovf_cnt, N,
                                      Wl, Wr, W1, wcat, w1t);

  int gblk = (N + 127) / 128;
  int schunks = (ET + tB - 1) / tB;
  int sxtra = (schunks + 1) / 2;
  int dchunks = (2 * npair2 + tB - 1) / tB;
  int dxtra = (dchunks + 1) / 2;

  // K2: edge-build FIRST ∪ gemm layer-0 (f32 A, in-reg f2bf) ∪ pair-dedup
  k_gemm_scatter<<<dim3(sxtra + gblk + dxtra, 2), tB, 0, stream>>>(
      x, wcat, N, C, xl_bf, xr_bf, sxtra, gblk,
      ei, deg, col32, ovf, ovf_cnt, E, ET,
      tp, fp, npair2, mark, nlist, ncnt);

  // layer 0 aggregate: all nodes (bf16 out + relu)
  gat_aggregate<<<(N * 64 + tB - 1) / tB, tB, 0, stream>>>(
      xl_bf, xr_bf, deg, col32, ovf, ovf_cnt, att, bias, nullptr, h1_bf,
      nullptr, nullptr, N, 1);

  // layer 1 gemm
  gemm_mfma<<<dim3(gblk, 2), tB, 0, stream>>>(h1_bf, wcat + (size_t)256 * 128, N, C, xl_bf, xr_bf);
  // layer 1 aggregate: only pair-referenced nodes (f32 out, no relu)
  int lblk = (2 * npair2 * 64 + tB - 1) / tB;   // worst case 32768 nodes
  gat_aggregate<<<lblk, tB, 0, stream>>>(
      xl_bf, xr_bf, deg, col32, ovf, ovf_cnt, att + C, bias + C, h1f, nullptr,
      nlist, ncnt, N, 0);

  // scorer: gather + GEMM + probs + loss fused
  gemm_scorer<<<P2 / 128, tB, 0, stream>>>(
      h1f, tp, fp, w1t, out_pos, b1, W2, b2, out_probs,
      lossacc, done_cnt, out_loss, P2, P);
}

// Round 23
// 174.108 us; speedup vs baseline: 1.0537x; 1.0537x over previous
//
#include <hip/hip_runtime.h>
#include <math.h>

#define C 128
#define OVF_CAP 32768

typedef unsigned short ushort_t;
typedef short short8 __attribute__((ext_vector_type(8)));
typedef float floatx4 __attribute__((ext_vector_type(4)));
typedef float fx2 __attribute__((ext_vector_type(2)));

__device__ __forceinline__ ushort_t f2bf(float x) {
  unsigned u = __float_as_uint(x);
  unsigned r = (u + 0x7FFFu + ((u >> 16) & 1u)) >> 16;
  return (ushort_t)r;
}
__device__ __forceinline__ fx2 bf2f2(unsigned u) {
  fx2 r;
  r.x = __uint_as_float(u << 16);
  r.y = __uint_as_float(u & 0xFFFF0000u);
  return r;
}

// ---------------- K0: init ws + weight prep ----------------

__global__ void k_init_prep(int* __restrict__ deg, int* __restrict__ mark,
                            float* __restrict__ lossacc,
                            unsigned* __restrict__ done_cnt, int* __restrict__ ncnt,
                            int* __restrict__ ovf_cnt, int n,
                            const float* __restrict__ Wl, const float* __restrict__ Wr,
                            const float* __restrict__ W1,
                            ushort_t* __restrict__ wcat, ushort_t* __restrict__ w1t) {
  int idx = blockIdx.x * blockDim.x + threadIdx.x;
  if (idx < n) { deg[idx] = 0; mark[idx] = 0; }
  if (idx == 0) { lossacc[0] = 0.f; done_cnt[0] = 0u; ncnt[0] = 0; ovf_cnt[0] = 0; }
  const int NCAT = 2 * 256 * 128;
  if (idx < NCAT) {
    int l = idx >> 15;
    int rem = idx & 32767;
    int nn = rem >> 7;
    int k = rem & 127;
    float v = (nn < 128) ? Wl[l * C * C + k * C + nn] : Wr[l * C * C + k * C + (nn - 128)];
    wcat[idx] = f2bf(v);
  } else if (idx < NCAT + 128 * 256) {
    int j = idx - NCAT;
    int nn = j >> 8;
    int k = j & 255;
    w1t[j] = f2bf(W1[k * C + nn]);
  }
}

// ---------------- bf16 MFMA GEMM (A = bf16 or f32 with in-reg convert) ----------------

__device__ __forceinline__ void gemm_body(
    const ushort_t* __restrict__ A, const float* __restrict__ Af,
    const ushort_t* __restrict__ Bt, int M, int K,
    ushort_t* __restrict__ outb0, ushort_t* __restrict__ outb1,
    int bx, int by) {
  int tid = threadIdx.x;
  int wave = tid >> 6, lane = tid & 63;
  int wm = (wave >> 1) * 64, wn = (wave & 1) * 64;
  int m_base = bx * 128 + wm;
  int lrow = lane & 15, lkg = lane >> 4;

  floatx4 acc[4][4];
  #pragma unroll
  for (int mi = 0; mi < 4; mi++)
    #pragma unroll
    for (int ni = 0; ni < 4; ni++)
      acc[mi][ni] = (floatx4){0.f, 0.f, 0.f, 0.f};

  const int ksteps = K >> 5;
  for (int ks = 0; ks < ksteps; ks++) {
    int koff = ks * 32 + lkg * 8;
    short8 af[4], bfr[4];
    #pragma unroll
    for (int mi = 0; mi < 4; mi++) {
      int gm = m_base + mi * 16 + lrow;
      gm = (gm < M) ? gm : (M - 1);
      if (Af) {
        const float* src = &Af[(size_t)gm * K + koff];
        float4 lo = *(const float4*)src;
        float4 hi = *(const float4*)(src + 4);
        short8 a;
        a[0] = (short)f2bf(lo.x); a[1] = (short)f2bf(lo.y);
        a[2] = (short)f2bf(lo.z); a[3] = (short)f2bf(lo.w);
        a[4] = (short)f2bf(hi.x); a[5] = (short)f2bf(hi.y);
        a[6] = (short)f2bf(hi.z); a[7] = (short)f2bf(hi.w);
        af[mi] = a;
      } else {
        af[mi] = *(const short8*)&A[(size_t)gm * K + koff];
      }
    }
    #pragma unroll
    for (int ni = 0; ni < 4; ni++) {
      int gn = by * 128 + wn + ni * 16 + lrow;
      bfr[ni] = *(const short8*)&Bt[(size_t)gn * K + koff];
    }
    #pragma unroll
    for (int mi = 0; mi < 4; mi++)
      #pragma unroll
      for (int ni = 0; ni < 4; ni++)
        acc[mi][ni] = __builtin_amdgcn_mfma_f32_16x16x32_bf16(af[mi], bfr[ni], acc[mi][ni], 0, 0, 0);
  }

  ushort_t* outb = (by == 0) ? outb0 : outb1;
  #pragma unroll
  for (int mi = 0; mi < 4; mi++) {
    #pragma unroll
    for (int r = 0; r < 4; r++) {
      int gm = m_base + mi * 16 + lkg * 4 + r;
      if (gm >= M) continue;
      #pragma unroll
      for (int ni = 0; ni < 4; ni++) {
        int nl = wn + ni * 16 + lrow;
        outb[(size_t)gm * 128 + nl] = f2bf(acc[mi][ni][r]);
      }
    }
  }
}

__global__ __launch_bounds__(256) void gemm_mfma(
    const ushort_t* __restrict__ A, const ushort_t* __restrict__ Bt,
    int M, int K,
    ushort_t* __restrict__ outb0, ushort_t* __restrict__ outb1) {
  gemm_body(A, nullptr, Bt, M, K, outb0, outb1, blockIdx.x, blockIdx.y);
}

// ---------------- K2: gemm layer-0 (f32 A) ∪ hist+scatter ∪ pair-dedup ----------------

__global__ __launch_bounds__(256) void k_gemm_scatter(
    const float* __restrict__ x, const ushort_t* __restrict__ Bt,
    int M, int K,
    ushort_t* __restrict__ outb0, ushort_t* __restrict__ outb1, int gb, int sx,
    const int* __restrict__ ei, int* __restrict__ deg,
    int* __restrict__ col32, int* __restrict__ ovf, int* __restrict__ ovf_cnt,
    int E, int ET,
    const int* __restrict__ tp, const int* __restrict__ fp, int npair2,
    int* __restrict__ mark, int* __restrict__ nlist, int* __restrict__ ncnt) {
  int bx = blockIdx.x;
  if (bx < gb) {
    gemm_body(nullptr, x, Bt, M, K, outb0, outb1, bx, blockIdx.y);
  } else if (bx < gb + sx) {
    int chunk = (bx - gb) * 2 + blockIdx.y;
    int e = chunk * 256 + threadIdx.x;
    if (e < ET) {
      int s, d;
      if (e < E) { s = ei[e]; d = ei[E + e]; }
      else { s = e - E; d = e - E; }        // self loop
      int p = atomicAdd(&deg[d], 1);
      if (p < 32) {
        col32[(d << 5) + p] = s;
      } else {
        int k = atomicAdd(ovf_cnt, 1);
        if (k < OVF_CAP) { ovf[2 * k] = d; ovf[2 * k + 1] = s; }
      }
    }
  } else {
    int chunk = (bx - gb - sx) * 2 + blockIdx.y;
    int i = chunk * 256 + threadIdx.x;
    if (i < 2 * npair2) {                   // dedup-append pair nodes
      int node = (i < npair2) ? tp[i] : fp[i - npair2];
      if (atomicExch(&mark[node], 1) == 0) {
        int k = atomicAdd(ncnt, 1);
        nlist[k] = node;
      }
    }
  }
}

// ---------------- GATv2 fused edge softmax + aggregation ----------------
// One wave per dst node; 4 groups x 16 lanes x 2 edges/iter. Fixed 32-slot
// CSR; slot loads unconditional with unsigned clamp. Overflow edges from
// tiny list, group-0 masked. exp2-domain logits. nlist: restricted mode.

__global__ __launch_bounds__(256) void gat_aggregate(
    const ushort_t* __restrict__ xl, const ushort_t* __restrict__ xr,
    const int* __restrict__ deg, const int* __restrict__ col32,
    const int* __restrict__ ovf, const int* __restrict__ ovf_cnt,
    const float* __restrict__ att, const float* __restrict__ bias,
    float* __restrict__ houtf, ushort_t* __restrict__ houtb,
    const int* __restrict__ nlist, const int* __restrict__ ncnt,
    int n, int do_relu) {
  int gwid = (int)((blockIdx.x * (size_t)blockDim.x + threadIdx.x) >> 6);
  int lane = threadIdx.x & 63;
  int wid;
  if (nlist) {
    if (gwid >= ncnt[0]) return;
    wid = nlist[gwid];
  } else {
    if (gwid >= n) return;
    wid = gwid;
  }
  int g = lane >> 4, p = lane & 15;
  int c0 = p * 8;
  const size_t i = wid;

  fx2 xri[4], av[4];
  {
    uint4 ur = *(const uint4*)&xr[i * C + c0];
    xri[0] = bf2f2(ur.x); xri[1] = bf2f2(ur.y);
    xri[2] = bf2f2(ur.z); xri[3] = bf2f2(ur.w);
    float4 a0 = *(const float4*)&att[c0];
    float4 a1 = *(const float4*)&att[c0 + 4];
    const float L2E = 1.44269504088896f;     // exp2-domain logits
    av[0] = (fx2){a0.x * L2E, a0.y * L2E}; av[1] = (fx2){a0.z * L2E, a0.w * L2E};
    av[2] = (fx2){a1.x * L2E, a1.y * L2E}; av[3] = (fx2){a1.z * L2E, a1.w * L2E};
  }

  int degc = deg[wid];
  int beg = wid << 5;
  int dmain = (degc < 32) ? degc : 32;
  int end = beg + dmain;
  float denom = 0.f;
  fx2 acc[4];
  #pragma unroll
  for (int q = 0; q < 4; q++) acc[q] = (fx2){0.f, 0.f};

  for (int base = beg; base < end; base += 8) {
    int e0 = base + g;
    int e1 = e0 + 4;
    unsigned j0 = min((unsigned)col32[e0], (unsigned)(n - 1));  // unconditional + clamp
    unsigned j1 = min((unsigned)col32[e1], (unsigned)(n - 1));
    uint4 r0 = *(const uint4*)&xl[((size_t)j0 << 7) + c0];
    uint4 r1 = *(const uint4*)&xl[((size_t)j1 << 7) + c0];
    fx2 x0[4], x1[4];
    x0[0] = bf2f2(r0.x); x0[1] = bf2f2(r0.y); x0[2] = bf2f2(r0.z); x0[3] = bf2f2(r0.w);
    x1[0] = bf2f2(r1.x); x1[1] = bf2f2(r1.y); x1[2] = bf2f2(r1.z); x1[3] = bf2f2(r1.w);

    fx2 d0 = (fx2){0.f, 0.f}, d1 = (fx2){0.f, 0.f};
    #pragma unroll
    for (int q = 0; q < 4; q++) {
      fx2 z0 = x0[q] + xri[q];
      fx2 z1 = x1[q] + xri[q];
      z0 = __builtin_elementwise_max(z0, z0 * 0.2f);
      z1 = __builtin_elementwise_max(z1, z1 * 0.2f);
      d0 = __builtin_elementwise_fma(z0, av[q], d0);
      d1 = __builtin_elementwise_fma(z1, av[q], d1);
    }
    float p0 = d0.x + d0.y;
    float p1 = d1.x + d1.y;
    #pragma unroll
    for (int off = 1; off <= 8; off <<= 1) {
      p0 += __shfl_xor(p0, off);
      p1 += __shfl_xor(p1, off);
    }
    float pe0 = (e0 < end) ? __builtin_amdgcn_exp2f(p0) : 0.f;
    float pe1 = (e1 < end) ? __builtin_amdgcn_exp2f(p1) : 0.f;
    denom += pe0 + pe1;
    fx2 v0 = (fx2){pe0, pe0}, v1 = (fx2){pe1, pe1};
    #pragma unroll
    for (int q = 0; q < 4; q++) {
      acc[q] = __builtin_elementwise_fma(v0, x0[q], acc[q]);
      acc[q] = __builtin_elementwise_fma(v1, x1[q], acc[q]);
    }
  }

  if (degc > 32) {                          // rare
    int oc = ovf_cnt[0];
    oc = (oc < OVF_CAP) ? oc : OVF_CAP;
    for (int t = 0; t < oc; t++) {
      if (ovf[2 * t] != wid) continue;
      unsigned j0 = min((unsigned)ovf[2 * t + 1], (unsigned)(n - 1));
      uint4 r0 = *(const uint4*)&xl[((size_t)j0 << 7) + c0];
      fx2 x0[4];
      x0[0] = bf2f2(r0.x); x0[1] = bf2f2(r0.y); x0[2] = bf2f2(r0.z); x0[3] = bf2f2(r0.w);
      fx2 d0 = (fx2){0.f, 0.f};
      #pragma unroll
      for (int q = 0; q < 4; q++) {
        fx2 z0 = x0[q] + xri[q];
        z0 = __builtin_elementwise_max(z0, z0 * 0.2f);
        d0 = __builtin_elementwise_fma(z0, av[q], d0);
      }
      float p0 = d0.x + d0.y;
      #pragma unroll
      for (int off = 1; off <= 8; off <<= 1)
        p0 += __shfl_xor(p0, off);
      float pe = (g == 0) ? __builtin_amdgcn_exp2f(p0) : 0.f;  // count once
      denom += pe;
      fx2 v0 = (fx2){pe, pe};
      #pragma unroll
      for (int q = 0; q < 4; q++)
        acc[q] = __builtin_elementwise_fma(v0, x0[q], acc[q]);
    }
  }

  #pragma unroll
  for (int off = 16; off <= 32; off <<= 1) {
    denom += __shfl_xor(denom, off);
    #pragma unroll
    for (int q = 0; q < 4; q++) {
      acc[q].x += __shfl_xor(acc[q].x, off);
      acc[q].y += __shfl_xor(acc[q].y, off);
    }
  }

  if (g == 0) {
    float inv = 1.f / denom;            // degree >= 1 via self loop
    float4 b0 = *(const float4*)&bias[c0];
    float4 b1 = *(const float4*)&bias[c0 + 4];
    float o[8];
    o[0] = acc[0].x*inv + b0.x; o[1] = acc[0].y*inv + b0.y;
    o[2] = acc[1].x*inv + b0.z; o[3] = acc[1].y*inv + b0.w;
    o[4] = acc[2].x*inv + b1.x; o[5] = acc[2].y*inv + b1.y;
    o[6] = acc[3].x*inv + b1.z; o[7] = acc[3].y*inv + b1.w;
    if (do_relu) {
      #pragma unroll
      for (int c = 0; c < 8; c++) o[c] = fmaxf(o[c], 0.f);
    }
    if (houtf) {
      *(float4*)&houtf[i * C + c0]     = make_float4(o[0], o[1], o[2], o[3]);
      *(float4*)&houtf[i * C + c0 + 4] = make_float4(o[4], o[5], o[6], o[7]);
    } else {
      short8 s;
      #pragma unroll
      for (int c = 0; c < 8; c++) s[c] = (short)f2bf(o[c]);
      *(short8*)&houtb[i * C + c0] = s;
    }
  }
}

// ---------------- scorer: fused pair-gather + GEMM + probs + loss ----------------

__global__ __launch_bounds__(256) void gemm_scorer(
    const float* __restrict__ h, const int* __restrict__ tp, const int* __restrict__ fp,
    const ushort_t* __restrict__ w1t, float* __restrict__ out_pos,
    const float* __restrict__ b1, const float* __restrict__ W2,
    const float* __restrict__ b2, float* __restrict__ probs_out,
    float* __restrict__ lossacc, unsigned* __restrict__ done_cnt,
    float* __restrict__ out_loss, int P2, int P) {
  __shared__ float lhalf[2][128];
  __shared__ float red[128];
  int tid = threadIdx.x;
  int wave = tid >> 6, lane = tid & 63;
  int wm = (wave >> 1) * 64, wn = (wave & 1) * 64;
  int m_base = blockIdx.x * 128 + wm;
  int lrow = lane & 15, lkg = lane >> 4;
  int half = P2 >> 1;
  bool emit = (wn == 0);

  int n0[4], n1[4];
  #pragma unroll
  for (int mi = 0; mi < 4; mi++) {
    int gm = m_base + mi * 16 + lrow;
    const int* pr = (gm < half) ? &tp[(size_t)gm * 2] : &fp[(size_t)(gm - half) * 2];
    n0[mi] = pr[0];
    n1[mi] = pr[1];
  }

  floatx4 acc[4][4];
  #pragma unroll
  for (int mi = 0; mi < 4; mi++)
    #pragma unroll
    for (int ni = 0; ni < 4; ni++)
      acc[mi][ni] = (floatx4){0.f, 0.f, 0.f, 0.f};

  #pragma unroll
  for (int ks = 0; ks < 8; ks++) {
    int koff = ks * 32 + lkg * 8;        // 0..248; ks<4 -> first node
    int chan = koff & 127;
    short8 af[4], bfr[4];
    #pragma unroll
    for (int mi = 0; mi < 4; mi++) {
      int node = (ks < 4) ? n0[mi] : n1[mi];
      const float* src = &h[(size_t)node * C + chan];
      float4 lo = *(const float4*)src;
      float4 hi = *(const float4*)(src + 4);
      if (emit) {
        int gm = m_base + mi * 16 + lrow;
        *(float4*)&out_pos[(size_t)gm * 256 + koff]     = lo;
        *(float4*)&out_pos[(size_t)gm * 256 + koff + 4] = hi;
      }
      short8 a;
      a[0] = (short)f2bf(lo.x); a[1] = (short)f2bf(lo.y);
      a[2] = (short)f2bf(lo.z); a[3] = (short)f2bf(lo.w);
      a[4] = (short)f2bf(hi.x); a[5] = (short)f2bf(hi.y);
      a[6] = (short)f2bf(hi.z); a[7] = (short)f2bf(hi.w);
      af[mi] = a;
    }
    #pragma unroll
    for (int ni = 0; ni < 4; ni++) {
      int gn = wn + ni * 16 + lrow;
      bfr[ni] = *(const short8*)&w1t[(size_t)gn * 256 + koff];
    }
    #pragma unroll
    for (int mi = 0; mi < 4; mi++)
      #pragma unroll
      for (int ni = 0; ni < 4; ni++)
        acc[mi][ni] = __builtin_amdgcn_mfma_f32_16x16x32_bf16(af[mi], bfr[ni], acc[mi][ni], 0, 0, 0);
  }

  // epilogue: hid = relu(acc + b1); partial W2-dot per wave-half in-register
  float b1v[4], w2v[4];
  #pragma unroll
  for (int ni = 0; ni < 4; ni++) {
    int nl = wn + ni * 16 + lrow;
    b1v[ni] = b1[nl];
    w2v[ni] = W2[nl];
  }
  #pragma unroll
  for (int mi = 0; mi < 4; mi++) {
    #pragma unroll
    for (int r = 0; r < 4; r++) {
      float ps = 0.f;
      #pragma unroll
      for (int ni = 0; ni < 4; ni++) {
        float v = fmaxf(acc[mi][ni][r] + b1v[ni], 0.f);
        ps = fmaf(v, w2v[ni], ps);
      }
      #pragma unroll
      for (int off = 1; off <= 8; off <<= 1)
        ps += __shfl_xor(ps, off);
      if (lrow == 0)
        lhalf[wn ? 1 : 0][wm + mi * 16 + lkg * 4 + r] = ps;
    }
  }
  __syncthreads();

  float term = 0.f;
  if (tid < 128) {
    int gr = blockIdx.x * 128 + tid;
    float s = lhalf[0][tid] + lhalf[1][tid] + b2[0];
    float pv = 1.f / (1.f + expf(-s));
    probs_out[gr] = pv;
    float pcl = fminf(fmaxf(pv, 1e-7f), 1.f - 1e-7f);
    term = (gr < P) ? logf(pcl) : log1pf(-pcl);
    red[tid] = term;
  }
  __syncthreads();
  if (tid < 64) red[tid] += red[tid + 64];
  __syncthreads();
  if (tid < 32) red[tid] += red[tid + 32];
  __syncthreads();
  if (tid == 0) {
    float s = 0.f;
    #pragma unroll
    for (int k = 0; k < 32; k++) s += red[k];
    atomicAdd(lossacc, s);
    __threadfence();
    unsigned prev = atomicAdd(done_cnt, 1u);
    if (prev == gridDim.x - 1) {
      float total = atomicAdd(lossacc, 0.f);    // coherent read
      out_loss[0] = -total / (float)P2;
    }
  }
}

// ---------------- launch ----------------

extern "C" void kernel_launch(void* const* d_in, const int* in_sizes, int n_in,
                              void* d_out, int out_size, void* d_ws, size_t ws_size,
                              hipStream_t stream) {
  const float* x    = (const float*)d_in[0];
  const int*   ei   = (const int*)d_in[1];
  const int*   tp   = (const int*)d_in[2];
  const int*   fp   = (const int*)d_in[3];
  const float* Wl   = (const float*)d_in[4];
  const float* Wr   = (const float*)d_in[5];
  const float* att  = (const float*)d_in[6];
  const float* bias = (const float*)d_in[7];
  const float* W1   = (const float*)d_in[8];
  const float* b1   = (const float*)d_in[9];
  const float* W2   = (const float*)d_in[10];
  const float* b2   = (const float*)d_in[11];

  int N  = in_sizes[0] / C;    // 50000
  int E  = in_sizes[1] / 2;    // 800000
  int P  = in_sizes[2] / 2;    // 8192
  int ET = E + N;
  int P2 = 2 * P;
  int npair2 = 2 * P;          // entries per pair array (P x 2)

  float* out       = (float*)d_out;
  float* out_pos   = out;                                  // [2P, 2C] (pos then neg)
  float* out_probs = out + (size_t)P2 * 2 * C;
  float* out_loss  = out_probs + P2;

  char* w = (char*)d_ws;
  size_t NCb2 = (size_t)N * C * 2;                         // bf16 [N,C]
  ushort_t* xl_bf = (ushort_t*)w;  w += NCb2;
  ushort_t* xr_bf = (ushort_t*)w;  w += NCb2;
  ushort_t* h1_bf = (ushort_t*)w;  w += NCb2;
  float* h1f = (float*)w;          w += (size_t)N * C * 4;
  ushort_t* wcat = (ushort_t*)w;   w += (size_t)2 * 256 * 128 * 2;
  ushort_t* w1t  = (ushort_t*)w;   w += (size_t)128 * 256 * 2;
  int* deg     = (int*)w;  w += (size_t)N * 4;
  int* mark    = (int*)w;  w += (size_t)N * 4;
  int* nlist   = (int*)w;  w += (size_t)(2 * npair2) * 4;
  int* col32   = (int*)w;  w += (size_t)N * 32 * 4;        // fixed-stride CSR slots
  int* ovf     = (int*)w;  w += (size_t)OVF_CAP * 2 * 4;   // overflow (d,s) pairs
  float* lossacc = (float*)w;  w += 16;
  unsigned* done_cnt = (unsigned*)w;  w += 16;
  int* ncnt    = (int*)w;  w += 16;
  int* ovf_cnt = (int*)w;

  const int tB = 256;

  // K0: init + weight prep
  k_init_prep<<<384, tB, 0, stream>>>(deg, mark, lossacc, done_cnt, ncnt, ovf_cnt, N,
                                      Wl, Wr, W1, wcat, w1t);

  int gblk = (N + 127) / 128;
  int schunks = (ET + tB - 1) / tB;
  int sxtra = (schunks + 1) / 2;
  int dchunks = (2 * npair2 + tB - 1) / tB;
  int dxtra = (dchunks + 1) / 2;

  // K2: gemm layer-0 (f32 A, in-reg f2bf) ∪ hist+scatter ∪ pair-dedup
  k_gemm_scatter<<<dim3(gblk + sxtra + dxtra, 2), tB, 0, stream>>>(
      x, wcat, N, C, xl_bf, xr_bf, gblk, sxtra,
      ei, deg, col32, ovf, ovf_cnt, E, ET,
      tp, fp, npair2, mark, nlist, ncnt);

  // layer 0 aggregate: all nodes (bf16 out + relu)
  gat_aggregate<<<(N * 64 + tB - 1) / tB, tB, 0, stream>>>(
      xl_bf, xr_bf, deg, col32, ovf, ovf_cnt, att, bias, nullptr, h1_bf,
      nullptr, nullptr, N, 1);

  // layer 1 gemm
  gemm_mfma<<<dim3(gblk, 2), tB, 0, stream>>>(h1_bf, wcat + (size_t)256 * 128, N, C, xl_bf, xr_bf);
  // layer 1 aggregate: only pair-referenced nodes (f32 out, no relu)
  int lblk = (2 * npair2 * 64 + tB - 1) / tB;   // worst case 32768 nodes
  gat_aggregate<<<lblk, tB, 0, stream>>>(
      xl_bf, xr_bf, deg, col32, ovf, ovf_cnt, att + C, bias + C, h1f, nullptr,
      nlist, ncnt, N, 0);

  // scorer: gather + GEMM + probs + loss fused
  gemm_scorer<<<P2 / 128, tB, 0, stream>>>(
      h1f, tp, fp, w1t, out_pos, b1, W2, b2, out_probs,
      lossacc, done_cnt, out_loss, P2, P);
}